// Round 4
// baseline (262.076 us; speedup 1.0000x reference)
//
#include <hip/hip_runtime.h>

// EMA recurrence: s_t = 0.9*s_{t-1} + 0.1*x_t
// x: (T=1024, 32, 1024) fp32, state: (32, 1024) fp32
// out = concat(all states (T,32,1024), final_state (32,1024))
//
// v5: compiler-safe wide-load pipeline.
// v4 post-mortem: inline-asm loads are invisible to SIInsertWaitcnts ->
// compiler-inserted register copies of in-flight asm-load dests read stale
// data (absmax 0.39). Fix: loads/stores are plain HIP (compiler emits
// correct counted vmcnt), and the pipeline SHAPE is enforced with
// sched_barrier(0) fences + __launch_bounds__(256,2) so the scheduler has
// no pressure incentive to collapse the double buffer (v2's failure,
// VGPR=28).
// Ceiling model (v1==v3 at 2.5 TB/s across 2x occupancy; float4-copy
// ubench = 6.3 TB/s): per-CU outstanding-VMEM is instruction-slot capped,
// so in-flight bytes = slots x bytes/instr. dword=256B/instr -> 2.5 TB/s;
// dwordx4=1KB/instr -> 4x. This kernel: 2 groups x 8 dwordx4 = 16 KB/wave
// nominally in flight.
// CHUNK=64, WARM=64 -> 16 chunks, 512 blocks, 8 waves/CU. Truncation err
// 0.9^64*|s| ~ 1.2e-3 (validated: v2 passed absmax 7.8e-3 at this config).

typedef float f32x4 __attribute__((ext_vector_type(4)));

constexpr int T = 1024;
constexpr int C = 32 * 1024;
constexpr int CV = C / 4;          // 8192 float4 columns per timestep
constexpr int CHUNK = 64;
constexpr int NCHUNK = T / CHUNK;  // 16
constexpr int WARM = 64;
constexpr int G = 8;               // float4 loads per group (8 KB/group)

__global__ __launch_bounds__(256, 2)
void ExponentialDecay_23708219474744_kernel(const f32x4* __restrict__ x4,
                                            const f32x4* __restrict__ state4,
                                            f32x4* __restrict__ out4) {
    const int cv = blockIdx.x * blockDim.x + threadIdx.x;  // 0..CV-1, coalesced
    const int chunk = blockIdx.y;
    const int t0 = chunk * CHUNK;
    const int tb = (chunk == 0) ? 0 : t0 - WARM;

    const float a = 0.9f;
    const float oma = 0.1f;

    f32x4 s;
    if (chunk == 0) {
        s = state4[cv];
    } else {
        s = (f32x4){0.0f, 0.0f, 0.0f, 0.0f};
    }

    const f32x4* __restrict__ lp = x4 + (size_t)tb * CV + cv;
    f32x4* __restrict__ op = out4 + (size_t)t0 * CV + cv;

    f32x4 A[G], B[G];

#define SB __builtin_amdgcn_sched_barrier(0)

#define REFILL(BUF) do {                                                  \
        _Pragma("unroll")                                                 \
        for (int i = 0; i < G; ++i) BUF[i] = lp[(size_t)i * CV];          \
        lp += (size_t)G * CV;                                             \
    } while (0)

#define EMA4(v) do {                                                      \
        s.x = fmaf(s.x, a, (v).x * oma);                                  \
        s.y = fmaf(s.y, a, (v).y * oma);                                  \
        s.z = fmaf(s.z, a, (v).z * oma);                                  \
        s.w = fmaf(s.w, a, (v).w * oma);                                  \
    } while (0)

#define CONSUME(BUF) do {                                                 \
        _Pragma("unroll")                                                 \
        for (int i = 0; i < G; ++i) EMA4(BUF[i]);                         \
    } while (0)

#define CONSUME_ST(BUF) do {                                              \
        _Pragma("unroll")                                                 \
        for (int i = 0; i < G; ++i) { EMA4(BUF[i]); op[(size_t)i * CV] = s; } \
        op += (size_t)G * CV;                                             \
    } while (0)

    // Prologue: 2 groups (16 dwordx4) in flight.
    REFILL(A);
    REFILL(B);
    SB;

    if (chunk != 0) {
        // Warm-up: 8 groups, EMA only. Each stage consumes one buffer and
        // refills it while the other buffer's loads are in flight; the
        // sched_barrier pins the refill inside its stage.
        #pragma unroll
        for (int w = 0; w < WARM / (2 * G); ++w) {  // 4 iterations
            CONSUME(A); REFILL(A); SB;
            CONSUME(B); REFILL(B); SB;
        }
    }

    // Main: 8 groups (CHUNK/G), stores interleaved with the EMA chain.
    CONSUME_ST(A); REFILL(A); SB;
    CONSUME_ST(B); REFILL(B); SB;
    CONSUME_ST(A); REFILL(A); SB;
    CONSUME_ST(B); REFILL(B); SB;
    CONSUME_ST(A); REFILL(A); SB;
    CONSUME_ST(B); REFILL(B); SB;
    CONSUME_ST(A); SB;   // no refill: last two groups already in flight
    CONSUME_ST(B);

    if (chunk == NCHUNK - 1) {
        out4[(size_t)T * CV + cv] = s;  // final_state
    }

#undef SB
#undef REFILL
#undef EMA4
#undef CONSUME
#undef CONSUME_ST
}

extern "C" void kernel_launch(void* const* d_in, const int* in_sizes, int n_in,
                              void* d_out, int out_size, void* d_ws, size_t ws_size,
                              hipStream_t stream) {
    const f32x4* x = (const f32x4*)d_in[0];
    const f32x4* state = (const f32x4*)d_in[1];
    f32x4* out = (f32x4*)d_out;

    dim3 block(256);
    dim3 grid(CV / 256, NCHUNK);  // (32, 16) = 512 blocks = 2048 waves = 8/CU
    ExponentialDecay_23708219474744_kernel<<<grid, block, 0, stream>>>(x, state, out);
}

// Round 6
// 255.824 us; speedup vs baseline: 1.0244x; 1.0244x over previous
//
#include <hip/hip_runtime.h>

// EMA recurrence: s_t = 0.9*s_{t-1} + 0.1*x_t
// x: (T=1024, 32, 1024) fp32, state: (32, 1024) fp32
// out = concat(all states (T,32,1024), final_state (32,1024))
//
// v6 (resubmit — round 5 was an infra failure, no data): two-pass
// associative scan — split into two PURE streams.
// Post-mortems v3/v5: ceiling ~2.5-2.7 TB/s is invariant to occupancy (8 vs
// 16 w/CU), load width (256B vs 1KB), and pipeline depth (VGPR=128 verified)
// => not latency-limited; the interleaved read/write + serial chain pattern
// itself caps throughput (same-chip float4 copy does 6.3 TB/s).
// Decomposition (EXACT, no warm-up approximation any more):
//   s_end(chunk c) = A * s_start(c) + L_c,  A = 0.9^CHUNK,
//   L_c = zero-init EMA over chunk c.
// Kernel 1 (pure read): L_c for c=0..14 -> workspace (120 MB read, 1.9 MB wr).
// Kernel 2: Horner prologue S_c = A*S + L_j (<=15 L2-hot loads), then run the
// chunk EMA from the exact start state (reads L3-warm x, streams 131 MB of
// stores). Plain-HIP v1-style codegen (unroll 8) — the compiler handles these
// loops well; no sched_barriers, no asm.

typedef float f32x4 __attribute__((ext_vector_type(4)));

constexpr int T = 1024;
constexpr int C = 32 * 1024;
constexpr int CV = C / 4;          // 8192 float4 columns per timestep
constexpr int CHUNK = 64;
constexpr int NCHUNK = T / CHUNK;  // 16
constexpr float A64 = 1.1790184577738602e-3f;  // 0.9^64

// ---------------- kernel 1: per-chunk local EMA (zero-init), chunks 0..14 ---
__global__ __launch_bounds__(256)
void ExponentialDecay_23708219474744_locals(const f32x4* __restrict__ x4,
                                            f32x4* __restrict__ L) {
    const int cv = blockIdx.x * blockDim.x + threadIdx.x;  // 0..CV-1
    const int c = blockIdx.y;                              // 0..NCHUNK-2
    const f32x4* __restrict__ xp = x4 + (size_t)c * CHUNK * CV + cv;

    const float a = 0.9f, oma = 0.1f;
    f32x4 s = {0.0f, 0.0f, 0.0f, 0.0f};
    #pragma unroll 8
    for (int t = 0; t < CHUNK; ++t) {
        f32x4 v = xp[(size_t)t * CV];
        s.x = fmaf(s.x, a, v.x * oma);
        s.y = fmaf(s.y, a, v.y * oma);
        s.z = fmaf(s.z, a, v.z * oma);
        s.w = fmaf(s.w, a, v.w * oma);
    }
    L[(size_t)c * CV + cv] = s;
}

// ---------------- kernel 2: exact start state via Horner, then stream out ---
__global__ __launch_bounds__(256)
void ExponentialDecay_23708219474744_kernel(const f32x4* __restrict__ x4,
                                            const f32x4* __restrict__ state4,
                                            const f32x4* __restrict__ L,
                                            f32x4* __restrict__ out4) {
    const int cv = blockIdx.x * blockDim.x + threadIdx.x;  // 0..CV-1
    const int c = blockIdx.y;                              // 0..NCHUNK-1
    const float a = 0.9f, oma = 0.1f;

    // S_c = A^c * s0 + sum_{j<c} A^{c-1-j} * L_j   (Horner, exact chain)
    f32x4 s = state4[cv];
    for (int j = 0; j < c; ++j) {
        f32x4 l = L[(size_t)j * CV + cv];
        s.x = fmaf(s.x, A64, l.x);
        s.y = fmaf(s.y, A64, l.y);
        s.z = fmaf(s.z, A64, l.z);
        s.w = fmaf(s.w, A64, l.w);
    }

    const f32x4* __restrict__ xp = x4 + (size_t)c * CHUNK * CV + cv;
    f32x4* __restrict__ op = out4 + (size_t)c * CHUNK * CV + cv;

    #pragma unroll 8
    for (int t = 0; t < CHUNK; ++t) {
        f32x4 v = xp[(size_t)t * CV];
        s.x = fmaf(s.x, a, v.x * oma);
        s.y = fmaf(s.y, a, v.y * oma);
        s.z = fmaf(s.z, a, v.z * oma);
        s.w = fmaf(s.w, a, v.w * oma);
        op[(size_t)t * CV] = s;
    }

    if (c == NCHUNK - 1) {
        out4[(size_t)T * CV + cv] = s;  // final_state
    }
}

extern "C" void kernel_launch(void* const* d_in, const int* in_sizes, int n_in,
                              void* d_out, int out_size, void* d_ws, size_t ws_size,
                              hipStream_t stream) {
    const f32x4* x = (const f32x4*)d_in[0];
    const f32x4* state = (const f32x4*)d_in[1];
    f32x4* out = (f32x4*)d_out;
    f32x4* L = (f32x4*)d_ws;  // (NCHUNK-1) * C floats = 1.92 MB workspace

    dim3 block(256);
    dim3 grid1(CV / 256, NCHUNK - 1);  // (32, 15): chunks 0..14
    ExponentialDecay_23708219474744_locals<<<grid1, block, 0, stream>>>(x, L);

    dim3 grid2(CV / 256, NCHUNK);      // (32, 16)
    ExponentialDecay_23708219474744_kernel<<<grid2, block, 0, stream>>>(x, state, L, out);
}